// Round 9
// baseline (149.416 us; speedup 1.0000x reference)
//
#include <hip/hip_runtime.h>
#include <hip/hip_bf16.h>
#include <cmath>

#define Bsz 8
#define Csz 512
#define Lsz 4096
#define LPOOL 511
#define NEGV -1000000000.0f

typedef __attribute__((ext_vector_type(8))) short short8;
typedef __attribute__((ext_vector_type(4))) float float4v;

__device__ __forceinline__ float bf2f(short u) {
  unsigned int x = ((unsigned int)(unsigned short)u) << 16;
  return __builtin_bit_cast(float, x);
}

// fast tanh: 1 - 2/(e^{2x}+1); rel err ~1e-5, far below bf16 gemm noise
__device__ __forceinline__ float ftanh(float x) {
  float e = __expf(2.0f * x);
  return 1.0f - 2.0f * __builtin_amdgcn_rcpf(e + 1.0f);
}

// ---------------------------------------------------------------------------
// prep: block 0 = mask-width detect; blocks 1..128 = W f32 -> Wts bf16 tiled.
__global__ __launch_bounds__(256) void prep(const unsigned char* __restrict__ mb,
    int* __restrict__ flag, const float* __restrict__ W,
    __hip_bfloat16* __restrict__ Wts) {
  const int tid = threadIdx.x;
  const int pb = blockIdx.x;
  if (pb == 0) {
    __shared__ int sf;
    if (tid == 0) sf = 0;
    __syncthreads();
    int f = 0;
    for (int i = tid; i < 4096; i += 256)
      if ((i & 3) && mb[i]) f = 1;
    if (f) atomicOr(&sf, 1);
    __syncthreads();
    if (tid == 0) *flag = sf;  // 0 = int32 mask, 1 = uint8 mask
  } else {
    int tg = (pb - 1) * 256 + tid;
    int d = tg >> 6, cg = tg & 63;
    float4 w0 = *(const float4*)(W + (size_t)d * 512 + cg * 8);
    float4 w1 = *(const float4*)(W + (size_t)d * 512 + cg * 8 + 4);
    __hip_bfloat16 hb[8];
    hb[0] = __float2bfloat16(w0.x); hb[1] = __float2bfloat16(w0.y);
    hb[2] = __float2bfloat16(w0.z); hb[3] = __float2bfloat16(w0.w);
    hb[4] = __float2bfloat16(w1.x); hb[5] = __float2bfloat16(w1.y);
    hb[6] = __float2bfloat16(w1.z); hb[7] = __float2bfloat16(w1.w);
    int nt = d >> 7, row = d & 127, ks = cg >> 2, seg = cg & 3;
    *(short8*)(Wts + (((size_t)nt * 16 + ks) * 512 + seg * 128 + row) * 8) = *(short8*)hb;
  }
}

// ---------------------------------------------------------------------------
// gemm_fused v8 (kept from R8, measured 43 us): 512 blocks x 256 thr (4 waves),
// 64 m-rows each, ~74.5 KiB LDS -> 2 blocks/CU. No barriers in hot loops.
// Phase 1: per-wave transpose (depth-3 global prefetch, pitch-21 LDS stage).
// Phase 2: barrier-free k-loop with depth-4 B register pipeline.
__global__ __launch_bounds__(256, 2) void gemm_fused(
    const float* __restrict__ x, const __hip_bfloat16* __restrict__ Wts,
    const float* __restrict__ bias, const float* __restrict__ v,
    float* __restrict__ s) {
  __shared__ short8 sA[4096];                    // 64 KiB: A 64m x 512k tiled
  __shared__ float sXw4[4][672];                 // 10.5 KiB: per-wave [32][21]

  const int tid = threadIdx.x;
  const int lane = tid & 63, wave = tid >> 6;
  const int mt = blockIdx.x;                     // 0..511
  const int b = mt >> 6;
  const int l0 = (mt & 63) << 6;                 // 64 l-rows per block

  // ---------------- phase 1: per-wave transpose, no block barriers ----------
  {
    float* sXw = sXw4[wave];
    const int r = lane >> 1;                     // c-row within 32-c chunk
    const int q = lane & 1;                      // 8-float half of wave's 16 l
    const int ll = lane & 15, ks2 = lane >> 4;   // read-side task
    const float* xg = x + (((size_t)(b * Csz + r)) << 12) + (size_t)(l0 + wave * 16 + q * 8);

    float4 A0a = *(const float4*)(xg);
    float4 A0b = *(const float4*)(xg + 4);
    float4 A1a = *(const float4*)(xg + (1u << 17));
    float4 A1b = *(const float4*)(xg + (1u << 17) + 4);
    float4 A2a = *(const float4*)(xg + (2u << 17));
    float4 A2b = *(const float4*)(xg + (2u << 17) + 4);

    #pragma unroll
    for (int cc = 0; cc < 16; ++cc) {
      float4 Na = A2a, Nb = A2b;
      if (cc < 13) {
        const float* xn = xg + ((size_t)(cc + 3) << 17);
        Na = *(const float4*)(xn);
        Nb = *(const float4*)(xn + 4);
      }
      // stage 8 floats elementwise (pitch 21: 2-way max bank aliasing)
      float* wp = &sXw[r * 21 + q * 8];
      wp[0] = A0a.x; wp[1] = A0a.y; wp[2] = A0a.z; wp[3] = A0a.w;
      wp[4] = A0b.x; wp[5] = A0b.y; wp[6] = A0b.z; wp[7] = A0b.w;
      // transposed read: 8 consecutive c's for one l (2-way banks, free)
      float tv[8];
      #pragma unroll
      for (int j = 0; j < 8; ++j) tv[j] = sXw[(ks2 * 8 + j) * 21 + ll];
      __hip_bfloat16 ab[8];
      #pragma unroll
      for (int j = 0; j < 8; ++j) ab[j] = __float2bfloat16(tv[j]);
      sA[(cc * 4 + ks2) * 64 + wave * 16 + ll] = *(short8*)ab;
      A0a = A1a; A0b = A1b; A1a = A2a; A1b = A2b; A2a = Na; A2b = Nb;
    }
  }

  const int lr = lane & 15, quad = lane >> 4;
  const int mh = wave >> 1, nh = wave & 1;

  __syncthreads();   // sA complete; phase 2 is read-only on LDS

  // ---------------- phase 2: barrier-free nt/k loop, depth-4 B pipeline -----
  const short8* Bp = (const short8*)Wts + quad * 128 + nh * 64 + lr;
#define LDB(dst, idx)                                                          \
  {                                                                            \
    const short8* bp = Bp + ((size_t)(idx) << 9);                              \
    dst[0] = bp[0]; dst[1] = bp[16]; dst[2] = bp[32]; dst[3] = bp[48];         \
  }
  short8 bq[4][4];                               // depth-4 pipeline, static idx
  LDB(bq[0], 0) LDB(bq[1], 1) LDB(bq[2], 2) LDB(bq[3], 3)

  float sp[2][4];
  #pragma unroll
  for (int mf = 0; mf < 2; ++mf)
    #pragma unroll
    for (int reg = 0; reg < 4; ++reg) sp[mf][reg] = 0.f;

  #pragma unroll
  for (int nt = 0; nt < 4; ++nt) {
    float bl[4], vl[4];
    #pragma unroll
    for (int nf = 0; nf < 4; ++nf) {
      int n = nt * 128 + nh * 64 + nf * 16 + lr;
      bl[nf] = bias[n];
      vl[nf] = v[n];
    }
    float4v acc[2][4];
    #pragma unroll
    for (int mf = 0; mf < 2; ++mf)
      #pragma unroll
      for (int nf = 0; nf < 4; ++nf) acc[mf][nf] = (float4v)0.f;

    #pragma unroll
    for (int ks = 0; ks < 16; ++ks) {
      const int idx = nt * 16 + ks;              // compile-time after unroll
      short8 af[2];
      af[0] = sA[(ks * 4 + quad) * 64 + mh * 32 + lr];
      af[1] = sA[(ks * 4 + quad) * 64 + mh * 32 + 16 + lr];
      __builtin_amdgcn_s_setprio(1);
      #pragma unroll
      for (int mf = 0; mf < 2; ++mf)
        #pragma unroll
        for (int nf = 0; nf < 4; ++nf)
          acc[mf][nf] = __builtin_amdgcn_mfma_f32_16x16x32_bf16(
              af[mf], bq[idx & 3][nf], acc[mf][nf], 0, 0, 0);
      __builtin_amdgcn_s_setprio(0);
      if (idx + 4 < 64) LDB(bq[idx & 3], idx + 4)   // refill consumed buffer
    }
    // epilogue for this nt (pure registers; overlaps in-flight B loads)
    #pragma unroll
    for (int mf = 0; mf < 2; ++mf)
      #pragma unroll
      for (int reg = 0; reg < 4; ++reg) {
        float pp = 0.f;
        #pragma unroll
        for (int nf = 0; nf < 4; ++nf)
          pp += ftanh(acc[mf][nf][reg] + bl[nf]) * vl[nf];
        sp[mf][reg] += pp;
      }
  }
#undef LDB

  // reduce over the 16 n-lanes; combine the two nh waves via staging space
  float* sRed = (float*)sXw4;              // 64 floats needed; sXw dead
  float pv[2][4];
  #pragma unroll
  for (int mf = 0; mf < 2; ++mf)
    #pragma unroll
    for (int reg = 0; reg < 4; ++reg) {
      float p = sp[mf][reg];
      p += __shfl_xor(p, 1, 16);
      p += __shfl_xor(p, 2, 16);
      p += __shfl_xor(p, 4, 16);
      p += __shfl_xor(p, 8, 16);
      pv[mf][reg] = p;
    }
  __syncthreads();                         // re-sync drifted waves before sRed
  if (nh == 1 && lr == 0) {
    #pragma unroll
    for (int mf = 0; mf < 2; ++mf)
      #pragma unroll
      for (int reg = 0; reg < 4; ++reg)
        sRed[((mh * 2 + mf) * 4 + quad) * 4 + reg] = pv[mf][reg];
  }
  __syncthreads();
  if (nh == 0 && lr == 0) {
    #pragma unroll
    for (int mf = 0; mf < 2; ++mf)
      #pragma unroll
      for (int reg = 0; reg < 4; ++reg)
        s[mt * 64 + mh * 32 + mf * 16 + quad * 4 + reg] =
            pv[mf][reg] + sRed[((mh * 2 + mf) * 4 + quad) * 4 + reg];
  }
}

// ---------------------------------------------------------------------------
// pool3: single fused softmax+pool kernel. Block = (b, group of 8 c-rows),
// grid 512 = 2 blocks/CU. Phase A: all 511 window softmaxes of this b into
// LDS wl[511][17] (pitch 17 -> conflict-free; redundant per c-group, cheap).
// Phase B: 8 rows sequentially with double-buffered 16 KB row stage:
// prefetch row cr+1 into registers while computing row cr's 511 dots;
// one __syncthreads per row. No wgt round-trip, no second launch.
__global__ __launch_bounds__(256) void pool3(const float* __restrict__ x,
    const float* __restrict__ s, const void* __restrict__ mask,
    const int* __restrict__ flag, float* __restrict__ out) {
  __shared__ float wl[LPOOL][17];              // 34.7 KB
  __shared__ float xrow[2][Lsz];               // 32 KB double buffer
  const int t = threadIdx.x;
  const int c0 = blockIdx.x * 8, b = blockIdx.y;

  // issue row-0 stage first so its HBM latency hides under softmax compute
  {
    const float* xr = x + ((size_t)(b * Csz + c0)) * Lsz;
    #pragma unroll
    for (int it = 0; it < 4; ++it) {
      int idx = (t + it * 256) * 4;
      *(float4*)(&xrow[0][idx]) = *(const float4*)(xr + idx);
    }
  }
  // phase A: softmax weights for all 511 windows of this b
  {
    const bool u8 = (*flag != 0);
    const unsigned char* m8 = (const unsigned char*)mask;
    const int* m32 = (const int*)mask;
    for (int p = t; p < LPOOL; p += 256) {
      const int base = b * Lsz + p * 8;
      float sv[16]; int mv[16];
      float mx = -3.4e38f;
      #pragma unroll
      for (int w = 0; w < 16; ++w) {
        int mk = u8 ? (int)m8[base + w] : m32[base + w];
        float val = mk ? NEGV : s[base + w];
        sv[w] = val; mv[w] = mk;
        mx = fmaxf(mx, val);
      }
      float sum = 0.f;
      #pragma unroll
      for (int w = 0; w < 16; ++w) { sv[w] = expf(sv[w] - mx); sum += sv[w]; }
      float inv = 1.0f / sum;
      float norm = 0.f;
      #pragma unroll
      for (int w = 0; w < 16; ++w) { sv[w] = mv[w] ? 0.f : sv[w] * inv; norm += sv[w]; }
      norm = fmaxf(norm, 1e-6f);
      float rn = 1.0f / norm;
      #pragma unroll
      for (int w = 0; w < 16; ++w) wl[p][w] = sv[w] * rn;
    }
  }
  __syncthreads();                             // row 0 staged + wl ready

  int cur = 0;
  for (int cr = 0; cr < 8; ++cr) {
    const int c = c0 + cr;
    // prefetch next row into registers (HBM latency hides under compute)
    float4 r0, r1, r2, r3;
    if (cr < 7) {
      const float* xn = x + ((size_t)(b * Csz + c + 1)) * Lsz + t * 4;
      r0 = *(const float4*)(xn);
      r1 = *(const float4*)(xn + 1024);
      r2 = *(const float4*)(xn + 2048);
      r3 = *(const float4*)(xn + 3072);
    }
    // compute 511 outputs for row c
    float* ob = out + ((size_t)(b * Csz + c)) * LPOOL;
    for (int p = t; p < LPOOL; p += 256) {
      const float* wp = &wl[p][0];
      const float* xp = &xrow[cur][p * 8];
      float acc = 0.f;
      #pragma unroll
      for (int qq = 0; qq < 16; ++qq) acc += xp[qq] * wp[qq];
      ob[p] = acc;
    }
    if (cr < 7) {
      // write prefetched row into the other buffer (safe: last reads of that
      // buffer were fenced by the sync at end of the previous iteration)
      float* xw = &xrow[cur ^ 1][t * 4];
      *(float4*)(xw)        = r0;
      *(float4*)(xw + 1024) = r1;
      *(float4*)(xw + 2048) = r2;
      *(float4*)(xw + 3072) = r3;
      __syncthreads();
      cur ^= 1;
    }
  }
}

// ---------------------------------------------------------------------------
// Fallback path kernels (only if ws too small for bf16 path)
__global__ void detect_mask(const unsigned char* __restrict__ mb, int* __restrict__ flag) {
  __shared__ int sf;
  int t = threadIdx.x;
  if (t == 0) sf = 0;
  __syncthreads();
  int f = 0;
  for (int i = t; i < 4096; i += 256)
    if ((i & 3) && mb[i]) f = 1;
  if (f) atomicOr(&sf, 1);
  __syncthreads();
  if (t == 0) *flag = sf;
}

__global__ void win_weights(const float* __restrict__ s, const void* __restrict__ mask,
                            const int* __restrict__ flag, float* __restrict__ wgt) {
  int t = blockIdx.x * blockDim.x + threadIdx.x;
  if (t >= Bsz * LPOOL) return;
  int b = t / LPOOL, p = t - b * LPOOL;
  const bool u8 = (*flag != 0);
  const unsigned char* m8 = (const unsigned char*)mask;
  const int* m32 = (const int*)mask;
  float sv[16]; int mv[16];
  float mx = -3.4e38f;
  int base = b * Lsz + p * 8;
  #pragma unroll
  for (int w = 0; w < 16; ++w) {
    int mk = u8 ? (int)m8[base + w] : m32[base + w];
    float val = mk ? NEGV : s[base + w];
    sv[w] = val; mv[w] = mk;
    mx = fmaxf(mx, val);
  }
  float sum = 0.f;
  #pragma unroll
  for (int w = 0; w < 16; ++w) { sv[w] = expf(sv[w] - mx); sum += sv[w]; }
  float inv = 1.0f / sum;
  float norm = 0.f;
  #pragma unroll
  for (int w = 0; w < 16; ++w) { sv[w] = mv[w] ? 0.f : sv[w] * inv; norm += sv[w]; }
  norm = fmaxf(norm, 1e-6f);
  float rn = 1.0f / norm;
  #pragma unroll
  for (int w = 0; w < 16; ++w) wgt[t * 16 + w] = sv[w] * rn;
}

__global__ __launch_bounds__(256) void pool_out(const float* __restrict__ x,
    const float* __restrict__ wgt, float* __restrict__ out) {
  __shared__ float xrow[Lsz];
  int bc = blockIdx.x;
  int c = bc & (Csz - 1);
  int b = bc >> 9;
  const float* xr = x + ((size_t)b * Csz + c) * Lsz;
  int tid = threadIdx.x;
  #pragma unroll
  for (int it = 0; it < 4; ++it) {
    int idx = (tid + it * 256) << 2;
    *(float4*)(&xrow[idx]) = *(const float4*)(&xr[idx]);
  }
  __syncthreads();
  const float* wb = wgt + (size_t)b * LPOOL * 16;
  float* ob = out + ((size_t)b * Csz + c) * LPOOL;
  for (int p = tid; p < LPOOL; p += 256) {
    const float4* wp = (const float4*)(wb + p * 16);
    const float4* xp = (const float4*)(&xrow[p * 8]);
    float acc = 0.f;
    #pragma unroll
    for (int q = 0; q < 4; ++q) {
      float4 wv = wp[q], xv = xp[q];
      acc += xv.x * wv.x + xv.y * wv.y + xv.z * wv.z + xv.w * wv.w;
    }
    ob[p] = acc;
  }
}

__global__ __launch_bounds__(256) void gemm_s_f32(const float* __restrict__ x,
    const float* __restrict__ W, const float* __restrict__ bias,
    const float* __restrict__ v, float* __restrict__ s_out) {
  __shared__ float sA[32][64];
  __shared__ float sB[32][68];
  __shared__ float s_acc[64];
  const int tid = threadIdx.x;
  const int b = blockIdx.y;
  const int l0 = blockIdx.x * 64;
  if (tid < 64) s_acc[tid] = 0.0f;
  const int tx = tid & 15;
  const int ty = tid >> 4;
  const float* xb = x + ((size_t)b * Csz) * Lsz + l0;
  for (int d0 = 0; d0 < Csz; d0 += 64) {
    float acc[4][4] = {{0.f}};
    for (int c0 = 0; c0 < Csz; c0 += 32) {
      __syncthreads();
      #pragma unroll
      for (int it = 0; it < 8; ++it) {
        int idx = tid + it * 256;
        int kc = idx >> 6, ml = idx & 63;
        sA[kc][ml] = xb[(size_t)(c0 + kc) * Lsz + ml];
      }
      #pragma unroll
      for (int it = 0; it < 8; ++it) {
        int idx = tid + it * 256;
        int kc = idx & 31, dj = idx >> 5;
        sB[kc][dj] = W[(size_t)(d0 + dj) * Csz + c0 + kc];
      }
      __syncthreads();
      #pragma unroll
      for (int kc = 0; kc < 32; ++kc) {
        float4 a  = *(const float4*)(&sA[kc][tx << 2]);
        float4 w4 = *(const float4*)(&sB[kc][ty << 2]);
        acc[0][0] += a.x * w4.x; acc[0][1] += a.x * w4.y; acc[0][2] += a.x * w4.z; acc[0][3] += a.x * w4.w;
        acc[1][0] += a.y * w4.x; acc[1][1] += a.y * w4.y; acc[1][2] += a.y * w4.z; acc[1][3] += a.y * w4.w;
        acc[2][0] += a.z * w4.x; acc[2][1] += a.z * w4.y; acc[2][2] += a.z * w4.z; acc[2][3] += a.z * w4.w;
        acc[3][0] += a.w * w4.x; acc[3][1] += a.w * w4.y; acc[3][2] += a.w * w4.z; acc[3][3] += a.w * w4.w;
      }
    }
    float part[4] = {0.f, 0.f, 0.f, 0.f};
    #pragma unroll
    for (int j = 0; j < 4; ++j) {
      int d = d0 + (ty << 2) + j;
      float bj = bias[d], vj = v[d];
      #pragma unroll
      for (int i = 0; i < 4; ++i)
        part[i] += tanhf(acc[i][j] + bj) * vj;
    }
    #pragma unroll
    for (int i = 0; i < 4; ++i)
      atomicAdd(&s_acc[(tx << 2) + i], part[i]);
  }
  __syncthreads();
  if (tid < 64) s_out[(size_t)b * Lsz + l0 + tid] = s_acc[tid];
}

// ---------------------------------------------------------------------------
extern "C" void kernel_launch(void* const* d_in, const int* in_sizes, int n_in,
                              void* d_out, int out_size, void* d_ws, size_t ws_size,
                              hipStream_t stream) {
  const float* x    = (const float*)d_in[0];
  const void*  mask = d_in[1];
  const float* W    = (const float*)d_in[2];
  const float* bias = (const float*)d_in[3];
  const float* v    = (const float*)d_in[4];
  float* out = (float*)d_out;

  char* wsb = (char*)d_ws;
  int*   flag = (int*)wsb;                                   // 256 B
  float* s    = (float*)(wsb + 256);                         // 131072 B
  float* wgt  = (float*)(wsb + 131328);                      // 261632 B (fallback)
  __hip_bfloat16* Wts = (__hip_bfloat16*)(wsb + 393216);     // 524288 B
  const size_t NEED = 917504;

  if (ws_size >= NEED) {
    prep<<<129, 256, 0, stream>>>((const unsigned char*)mask, flag, W, Wts);
    gemm_fused<<<512, 256, 0, stream>>>(x, Wts, bias, v, s);
    pool3<<<dim3(64, Bsz), 256, 0, stream>>>(x, s, mask, flag, out);
  } else {
    detect_mask<<<1, 256, 0, stream>>>((const unsigned char*)mask, flag);
    gemm_s_f32<<<dim3(Lsz / 64, Bsz), 256, 0, stream>>>(x, W, bias, v, s);
    win_weights<<<(Bsz * LPOOL + 255) / 256, 256, 0, stream>>>(s, mask, flag, wgt);
    pool_out<<<Bsz * Csz, 256, 0, stream>>>(x, wgt, out);
  }
}

// Round 10
// 139.618 us; speedup vs baseline: 1.0702x; 1.0702x over previous
//
#include <hip/hip_runtime.h>
#include <hip/hip_bf16.h>
#include <cmath>

#define Bsz 8
#define Csz 512
#define Lsz 4096
#define LPOOL 511
#define NEGV -1000000000.0f

typedef __attribute__((ext_vector_type(8))) short short8;
typedef __attribute__((ext_vector_type(4))) float float4v;

__device__ __forceinline__ float bf2f(short u) {
  unsigned int x = ((unsigned int)(unsigned short)u) << 16;
  return __builtin_bit_cast(float, x);
}

// fast tanh: 1 - 2/(e^{2x}+1); rel err ~1e-5, far below bf16 gemm noise
__device__ __forceinline__ float ftanh(float x) {
  float e = __expf(2.0f * x);
  return 1.0f - 2.0f * __builtin_amdgcn_rcpf(e + 1.0f);
}

// ---------------------------------------------------------------------------
// prep: block 0 = mask-width detect; blocks 1..128 = W f32 -> Wts bf16 tiled.
__global__ __launch_bounds__(256) void prep(const unsigned char* __restrict__ mb,
    int* __restrict__ flag, const float* __restrict__ W,
    __hip_bfloat16* __restrict__ Wts) {
  const int tid = threadIdx.x;
  const int pb = blockIdx.x;
  if (pb == 0) {
    __shared__ int sf;
    if (tid == 0) sf = 0;
    __syncthreads();
    int f = 0;
    for (int i = tid; i < 4096; i += 256)
      if ((i & 3) && mb[i]) f = 1;
    if (f) atomicOr(&sf, 1);
    __syncthreads();
    if (tid == 0) *flag = sf;  // 0 = int32 mask, 1 = uint8 mask
  } else {
    int tg = (pb - 1) * 256 + tid;
    int d = tg >> 6, cg = tg & 63;
    float4 w0 = *(const float4*)(W + (size_t)d * 512 + cg * 8);
    float4 w1 = *(const float4*)(W + (size_t)d * 512 + cg * 8 + 4);
    __hip_bfloat16 hb[8];
    hb[0] = __float2bfloat16(w0.x); hb[1] = __float2bfloat16(w0.y);
    hb[2] = __float2bfloat16(w0.z); hb[3] = __float2bfloat16(w0.w);
    hb[4] = __float2bfloat16(w1.x); hb[5] = __float2bfloat16(w1.y);
    hb[6] = __float2bfloat16(w1.z); hb[7] = __float2bfloat16(w1.w);
    int nt = d >> 7, row = d & 127, ks = cg >> 2, seg = cg & 3;
    *(short8*)(Wts + (((size_t)nt * 16 + ks) * 512 + seg * 128 + row) * 8) = *(short8*)hb;
  }
}

// ---------------------------------------------------------------------------
// gemm_fused v8 (unchanged from R8, measured 43.7 us): 512 blocks x 256 thr,
// 64 m-rows each, ~74.5 KiB LDS -> 2 blocks/CU. No barriers in hot loops.
// Phase 1: per-wave transpose (depth-3 global prefetch, pitch-21 LDS stage).
// Phase 2: barrier-free k-loop with depth-4 B register pipeline.
__global__ __launch_bounds__(256, 2) void gemm_fused(
    const float* __restrict__ x, const __hip_bfloat16* __restrict__ Wts,
    const float* __restrict__ bias, const float* __restrict__ v,
    float* __restrict__ s) {
  __shared__ short8 sA[4096];                    // 64 KiB: A 64m x 512k tiled
  __shared__ float sXw4[4][672];                 // 10.5 KiB: per-wave [32][21]

  const int tid = threadIdx.x;
  const int lane = tid & 63, wave = tid >> 6;
  const int mt = blockIdx.x;                     // 0..511
  const int b = mt >> 6;
  const int l0 = (mt & 63) << 6;                 // 64 l-rows per block

  // ---------------- phase 1: per-wave transpose, no block barriers ----------
  {
    float* sXw = sXw4[wave];
    const int r = lane >> 1;                     // c-row within 32-c chunk
    const int q = lane & 1;                      // 8-float half of wave's 16 l
    const int ll = lane & 15, ks2 = lane >> 4;   // read-side task
    const float* xg = x + (((size_t)(b * Csz + r)) << 12) + (size_t)(l0 + wave * 16 + q * 8);

    float4 A0a = *(const float4*)(xg);
    float4 A0b = *(const float4*)(xg + 4);
    float4 A1a = *(const float4*)(xg + (1u << 17));
    float4 A1b = *(const float4*)(xg + (1u << 17) + 4);
    float4 A2a = *(const float4*)(xg + (2u << 17));
    float4 A2b = *(const float4*)(xg + (2u << 17) + 4);

    #pragma unroll
    for (int cc = 0; cc < 16; ++cc) {
      float4 Na = A2a, Nb = A2b;
      if (cc < 13) {
        const float* xn = xg + ((size_t)(cc + 3) << 17);
        Na = *(const float4*)(xn);
        Nb = *(const float4*)(xn + 4);
      }
      // stage 8 floats elementwise (pitch 21: 2-way max bank aliasing)
      float* wp = &sXw[r * 21 + q * 8];
      wp[0] = A0a.x; wp[1] = A0a.y; wp[2] = A0a.z; wp[3] = A0a.w;
      wp[4] = A0b.x; wp[5] = A0b.y; wp[6] = A0b.z; wp[7] = A0b.w;
      // transposed read: 8 consecutive c's for one l (2-way banks, free)
      float tv[8];
      #pragma unroll
      for (int j = 0; j < 8; ++j) tv[j] = sXw[(ks2 * 8 + j) * 21 + ll];
      __hip_bfloat16 ab[8];
      #pragma unroll
      for (int j = 0; j < 8; ++j) ab[j] = __float2bfloat16(tv[j]);
      sA[(cc * 4 + ks2) * 64 + wave * 16 + ll] = *(short8*)ab;
      A0a = A1a; A0b = A1b; A1a = A2a; A1b = A2b; A2a = Na; A2b = Nb;
    }
  }

  const int lr = lane & 15, quad = lane >> 4;
  const int mh = wave >> 1, nh = wave & 1;

  __syncthreads();   // sA complete; phase 2 is read-only on LDS

  // ---------------- phase 2: barrier-free nt/k loop, depth-4 B pipeline -----
  const short8* Bp = (const short8*)Wts + quad * 128 + nh * 64 + lr;
#define LDB(dst, idx)                                                          \
  {                                                                            \
    const short8* bp = Bp + ((size_t)(idx) << 9);                              \
    dst[0] = bp[0]; dst[1] = bp[16]; dst[2] = bp[32]; dst[3] = bp[48];         \
  }
  short8 bq[4][4];                               // depth-4 pipeline, static idx
  LDB(bq[0], 0) LDB(bq[1], 1) LDB(bq[2], 2) LDB(bq[3], 3)

  float sp[2][4];
  #pragma unroll
  for (int mf = 0; mf < 2; ++mf)
    #pragma unroll
    for (int reg = 0; reg < 4; ++reg) sp[mf][reg] = 0.f;

  #pragma unroll
  for (int nt = 0; nt < 4; ++nt) {
    float bl[4], vl[4];
    #pragma unroll
    for (int nf = 0; nf < 4; ++nf) {
      int n = nt * 128 + nh * 64 + nf * 16 + lr;
      bl[nf] = bias[n];
      vl[nf] = v[n];
    }
    float4v acc[2][4];
    #pragma unroll
    for (int mf = 0; mf < 2; ++mf)
      #pragma unroll
      for (int nf = 0; nf < 4; ++nf) acc[mf][nf] = (float4v)0.f;

    #pragma unroll
    for (int ks = 0; ks < 16; ++ks) {
      const int idx = nt * 16 + ks;              // compile-time after unroll
      short8 af[2];
      af[0] = sA[(ks * 4 + quad) * 64 + mh * 32 + lr];
      af[1] = sA[(ks * 4 + quad) * 64 + mh * 32 + 16 + lr];
      __builtin_amdgcn_s_setprio(1);
      #pragma unroll
      for (int mf = 0; mf < 2; ++mf)
        #pragma unroll
        for (int nf = 0; nf < 4; ++nf)
          acc[mf][nf] = __builtin_amdgcn_mfma_f32_16x16x32_bf16(
              af[mf], bq[idx & 3][nf], acc[mf][nf], 0, 0, 0);
      __builtin_amdgcn_s_setprio(0);
      if (idx + 4 < 64) LDB(bq[idx & 3], idx + 4)   // refill consumed buffer
    }
    // epilogue for this nt (pure registers; overlaps in-flight B loads)
    #pragma unroll
    for (int mf = 0; mf < 2; ++mf)
      #pragma unroll
      for (int reg = 0; reg < 4; ++reg) {
        float pp = 0.f;
        #pragma unroll
        for (int nf = 0; nf < 4; ++nf)
          pp += ftanh(acc[mf][nf][reg] + bl[nf]) * vl[nf];
        sp[mf][reg] += pp;
      }
  }
#undef LDB

  // reduce over the 16 n-lanes; combine the two nh waves via staging space
  float* sRed = (float*)sXw4;              // 64 floats needed; sXw dead
  float pv[2][4];
  #pragma unroll
  for (int mf = 0; mf < 2; ++mf)
    #pragma unroll
    for (int reg = 0; reg < 4; ++reg) {
      float p = sp[mf][reg];
      p += __shfl_xor(p, 1, 16);
      p += __shfl_xor(p, 2, 16);
      p += __shfl_xor(p, 4, 16);
      p += __shfl_xor(p, 8, 16);
      pv[mf][reg] = p;
    }
  __syncthreads();                         // re-sync drifted waves before sRed
  if (nh == 1 && lr == 0) {
    #pragma unroll
    for (int mf = 0; mf < 2; ++mf)
      #pragma unroll
      for (int reg = 0; reg < 4; ++reg)
        sRed[((mh * 2 + mf) * 4 + quad) * 4 + reg] = pv[mf][reg];
  }
  __syncthreads();
  if (nh == 0 && lr == 0) {
    #pragma unroll
    for (int mf = 0; mf < 2; ++mf)
      #pragma unroll
      for (int reg = 0; reg < 4; ++reg)
        s[mt * 64 + mh * 32 + mf * 16 + quad * 4 + reg] =
            pv[mf][reg] + sRed[((mh * 2 + mf) * 4 + quad) * 4 + reg];
  }
}

// ---------------------------------------------------------------------------
// pool3 v2: fused softmax+pool, bank-conflict-free row buffer.
// PX(i) = i + (i>>3): 1-float pad per 8 -> window reads are stride-9,
// gcd(9,32)=1 -> all 32 banks, 2-way max (was 16-way at stride 8).
// Block = (b, group of 8 c-rows), grid 512 = 2 blocks/CU.
// Phase A: all 511 window softmaxes of this b into wl[511][17] (vectorized
// s/mask loads). Phase B: 8 rows, double-buffered padded row stage with
// register prefetch; one __syncthreads per row.
#define PX(i) ((i) + ((i) >> 3))
__global__ __launch_bounds__(256) void pool3(const float* __restrict__ x,
    const float* __restrict__ s, const void* __restrict__ mask,
    const int* __restrict__ flag, float* __restrict__ out) {
  __shared__ float wl[LPOOL][17];              // 34.7 KB
  __shared__ float xrow[2][4608];               // 36 KB padded double buffer
  const int t = threadIdx.x;
  const int c0 = blockIdx.x * 8, b = blockIdx.y;

  // issue row-0 stage first so its HBM latency hides under softmax compute
  {
    const float* xr = x + ((size_t)(b * Csz + c0)) * Lsz;
    #pragma unroll
    for (int it = 0; it < 4; ++it) {
      int i0 = (t + it * 256) * 4;
      float4 vv = *(const float4*)(xr + i0);
      int o = PX(i0);                          // i0%4==0 -> PX(i0+k)=PX(i0)+k
      xrow[0][o + 0] = vv.x; xrow[0][o + 1] = vv.y;
      xrow[0][o + 2] = vv.z; xrow[0][o + 3] = vv.w;
    }
  }
  // phase A: softmax weights for all 511 windows of this b (vector loads)
  {
    const bool u8 = (*flag != 0);
    for (int p = t; p < LPOOL; p += 256) {
      const int base = b * Lsz + p * 8;
      float4 s0 = *(const float4*)(s + base);
      float4 s1 = *(const float4*)(s + base + 4);
      float4 s2 = *(const float4*)(s + base + 8);
      float4 s3 = *(const float4*)(s + base + 12);
      float sv[16] = {s0.x, s0.y, s0.z, s0.w, s1.x, s1.y, s1.z, s1.w,
                      s2.x, s2.y, s2.z, s2.w, s3.x, s3.y, s3.z, s3.w};
      int mv[16];
      if (u8) {
        const unsigned long long* m64 =
            (const unsigned long long*)((const unsigned char*)mask + base);
        unsigned long long ma = m64[0], mb2 = m64[1];
        #pragma unroll
        for (int w = 0; w < 8; ++w) {
          mv[w]     = (int)((ma  >> (8 * w)) & 0xff);
          mv[w + 8] = (int)((mb2 >> (8 * w)) & 0xff);
        }
      } else {
        const int4* mi = (const int4*)((const int*)mask + base);
        int4 a = mi[0], bb = mi[1], cc = mi[2], dd = mi[3];
        mv[0] = a.x;  mv[1] = a.y;  mv[2] = a.z;  mv[3] = a.w;
        mv[4] = bb.x; mv[5] = bb.y; mv[6] = bb.z; mv[7] = bb.w;
        mv[8] = cc.x; mv[9] = cc.y; mv[10] = cc.z; mv[11] = cc.w;
        mv[12] = dd.x; mv[13] = dd.y; mv[14] = dd.z; mv[15] = dd.w;
      }
      float mx = -3.4e38f;
      #pragma unroll
      for (int w = 0; w < 16; ++w) {
        sv[w] = mv[w] ? NEGV : sv[w];
        mx = fmaxf(mx, sv[w]);
      }
      float sum = 0.f;
      #pragma unroll
      for (int w = 0; w < 16; ++w) { sv[w] = expf(sv[w] - mx); sum += sv[w]; }
      float inv = 1.0f / sum;
      float norm = 0.f;
      #pragma unroll
      for (int w = 0; w < 16; ++w) { sv[w] = mv[w] ? 0.f : sv[w] * inv; norm += sv[w]; }
      norm = fmaxf(norm, 1e-6f);
      float rn = 1.0f / norm;
      #pragma unroll
      for (int w = 0; w < 16; ++w) wl[p][w] = sv[w] * rn;
    }
  }
  __syncthreads();                             // row 0 staged + wl ready

  int cur = 0;
  for (int cr = 0; cr < 8; ++cr) {
    const int c = c0 + cr;
    // prefetch next row into registers (HBM latency hides under compute)
    float4 r0, r1, r2, r3;
    if (cr < 7) {
      const float* xn = x + ((size_t)(b * Csz + c + 1)) * Lsz + t * 4;
      r0 = *(const float4*)(xn);
      r1 = *(const float4*)(xn + 1024);
      r2 = *(const float4*)(xn + 2048);
      r3 = *(const float4*)(xn + 3072);
    }
    // compute 511 outputs for row c (stride-9 reads: conflict-free)
    float* ob = out + ((size_t)(b * Csz + c)) * LPOOL;
    for (int p = t; p < LPOOL; p += 256) {
      const float* wp = &wl[p][0];
      const float* xp0 = &xrow[cur][PX(p * 8)];       // 8 contiguous
      const float* xp1 = &xrow[cur][PX(p * 8 + 8)];   // next 8 contiguous
      float acc = 0.f;
      #pragma unroll
      for (int qq = 0; qq < 8; ++qq) acc += xp0[qq] * wp[qq];
      #pragma unroll
      for (int qq = 0; qq < 8; ++qq) acc += xp1[qq] * wp[8 + qq];
      ob[p] = acc;
    }
    if (cr < 7) {
      // write prefetched row into the other buffer (reads of that buffer
      // were fenced by the sync at end of the previous iteration)
      float* xw = &xrow[cur ^ 1][0];
      {
        int i0 = t * 4;        int o = PX(i0);
        xw[o] = r0.x; xw[o + 1] = r0.y; xw[o + 2] = r0.z; xw[o + 3] = r0.w;
        i0 = t * 4 + 1024;     o = PX(i0);
        xw[o] = r1.x; xw[o + 1] = r1.y; xw[o + 2] = r1.z; xw[o + 3] = r1.w;
        i0 = t * 4 + 2048;     o = PX(i0);
        xw[o] = r2.x; xw[o + 1] = r2.y; xw[o + 2] = r2.z; xw[o + 3] = r2.w;
        i0 = t * 4 + 3072;     o = PX(i0);
        xw[o] = r3.x; xw[o + 1] = r3.y; xw[o + 2] = r3.z; xw[o + 3] = r3.w;
      }
      __syncthreads();
      cur ^= 1;
    }
  }
}
#undef PX

// ---------------------------------------------------------------------------
// Fallback path kernels (only if ws too small for bf16 path)
__global__ void detect_mask(const unsigned char* __restrict__ mb, int* __restrict__ flag) {
  __shared__ int sf;
  int t = threadIdx.x;
  if (t == 0) sf = 0;
  __syncthreads();
  int f = 0;
  for (int i = t; i < 4096; i += 256)
    if ((i & 3) && mb[i]) f = 1;
  if (f) atomicOr(&sf, 1);
  __syncthreads();
  if (t == 0) *flag = sf;
}

__global__ void win_weights(const float* __restrict__ s, const void* __restrict__ mask,
                            const int* __restrict__ flag, float* __restrict__ wgt) {
  int t = blockIdx.x * blockDim.x + threadIdx.x;
  if (t >= Bsz * LPOOL) return;
  int b = t / LPOOL, p = t - b * LPOOL;
  const bool u8 = (*flag != 0);
  const unsigned char* m8 = (const unsigned char*)mask;
  const int* m32 = (const int*)mask;
  float sv[16]; int mv[16];
  float mx = -3.4e38f;
  int base = b * Lsz + p * 8;
  #pragma unroll
  for (int w = 0; w < 16; ++w) {
    int mk = u8 ? (int)m8[base + w] : m32[base + w];
    float val = mk ? NEGV : s[base + w];
    sv[w] = val; mv[w] = mk;
    mx = fmaxf(mx, val);
  }
  float sum = 0.f;
  #pragma unroll
  for (int w = 0; w < 16; ++w) { sv[w] = expf(sv[w] - mx); sum += sv[w]; }
  float inv = 1.0f / sum;
  float norm = 0.f;
  #pragma unroll
  for (int w = 0; w < 16; ++w) { sv[w] = mv[w] ? 0.f : sv[w] * inv; norm += sv[w]; }
  norm = fmaxf(norm, 1e-6f);
  float rn = 1.0f / norm;
  #pragma unroll
  for (int w = 0; w < 16; ++w) wgt[t * 16 + w] = sv[w] * rn;
}

__global__ __launch_bounds__(256) void pool_out(const float* __restrict__ x,
    const float* __restrict__ wgt, float* __restrict__ out) {
  __shared__ float xrow[Lsz];
  int bc = blockIdx.x;
  int c = bc & (Csz - 1);
  int b = bc >> 9;
  const float* xr = x + ((size_t)b * Csz + c) * Lsz;
  int tid = threadIdx.x;
  #pragma unroll
  for (int it = 0; it < 4; ++it) {
    int idx = (tid + it * 256) << 2;
    *(float4*)(&xrow[idx]) = *(const float4*)(&xr[idx]);
  }
  __syncthreads();
  const float* wb = wgt + (size_t)b * LPOOL * 16;
  float* ob = out + ((size_t)b * Csz + c) * LPOOL;
  for (int p = tid; p < LPOOL; p += 256) {
    const float4* wp = (const float4*)(wb + p * 16);
    const float4* xp = (const float4*)(&xrow[p * 8]);
    float acc = 0.f;
    #pragma unroll
    for (int q = 0; q < 4; ++q) {
      float4 wv = wp[q], xv = xp[q];
      acc += xv.x * wv.x + xv.y * wv.y + xv.z * wv.z + xv.w * wv.w;
    }
    ob[p] = acc;
  }
}

__global__ __launch_bounds__(256) void gemm_s_f32(const float* __restrict__ x,
    const float* __restrict__ W, const float* __restrict__ bias,
    const float* __restrict__ v, float* __restrict__ s_out) {
  __shared__ float sA[32][64];
  __shared__ float sB[32][68];
  __shared__ float s_acc[64];
  const int tid = threadIdx.x;
  const int b = blockIdx.y;
  const int l0 = blockIdx.x * 64;
  if (tid < 64) s_acc[tid] = 0.0f;
  const int tx = tid & 15;
  const int ty = tid >> 4;
  const float* xb = x + ((size_t)b * Csz) * Lsz + l0;
  for (int d0 = 0; d0 < Csz; d0 += 64) {
    float acc[4][4] = {{0.f}};
    for (int c0 = 0; c0 < Csz; c0 += 32) {
      __syncthreads();
      #pragma unroll
      for (int it = 0; it < 8; ++it) {
        int idx = tid + it * 256;
        int kc = idx >> 6, ml = idx & 63;
        sA[kc][ml] = xb[(size_t)(c0 + kc) * Lsz + ml];
      }
      #pragma unroll
      for (int it = 0; it < 8; ++it) {
        int idx = tid + it * 256;
        int kc = idx & 31, dj = idx >> 5;
        sB[kc][dj] = W[(size_t)(d0 + dj) * Csz + c0 + kc];
      }
      __syncthreads();
      #pragma unroll
      for (int kc = 0; kc < 32; ++kc) {
        float4 a  = *(const float4*)(&sA[kc][tx << 2]);
        float4 w4 = *(const float4*)(&sB[kc][ty << 2]);
        acc[0][0] += a.x * w4.x; acc[0][1] += a.x * w4.y; acc[0][2] += a.x * w4.z; acc[0][3] += a.x * w4.w;
        acc[1][0] += a.y * w4.x; acc[1][1] += a.y * w4.y; acc[1][2] += a.y * w4.z; acc[1][3] += a.y * w4.w;
        acc[2][0] += a.z * w4.x; acc[2][1] += a.z * w4.y; acc[2][2] += a.z * w4.z; acc[2][3] += a.z * w4.w;
        acc[3][0] += a.w * w4.x; acc[3][1] += a.w * w4.y; acc[3][2] += a.w * w4.z; acc[3][3] += a.w * w4.w;
      }
    }
    float part[4] = {0.f, 0.f, 0.f, 0.f};
    #pragma unroll
    for (int j = 0; j < 4; ++j) {
      int d = d0 + (ty << 2) + j;
      float bj = bias[d], vj = v[d];
      #pragma unroll
      for (int i = 0; i < 4; ++i)
        part[i] += tanhf(acc[i][j] + bj) * vj;
    }
    #pragma unroll
    for (int i = 0; i < 4; ++i)
      atomicAdd(&s_acc[(tx << 2) + i], part[i]);
  }
  __syncthreads();
  if (tid < 64) s_out[(size_t)b * Lsz + l0 + tid] = s_acc[tid];
}

// ---------------------------------------------------------------------------
extern "C" void kernel_launch(void* const* d_in, const int* in_sizes, int n_in,
                              void* d_out, int out_size, void* d_ws, size_t ws_size,
                              hipStream_t stream) {
  const float* x    = (const float*)d_in[0];
  const void*  mask = d_in[1];
  const float* W    = (const float*)d_in[2];
  const float* bias = (const float*)d_in[3];
  const float* v    = (const float*)d_in[4];
  float* out = (float*)d_out;

  char* wsb = (char*)d_ws;
  int*   flag = (int*)wsb;                                   // 256 B
  float* s    = (float*)(wsb + 256);                         // 131072 B
  float* wgt  = (float*)(wsb + 131328);                      // 261632 B (fallback)
  __hip_bfloat16* Wts = (__hip_bfloat16*)(wsb + 393216);     // 524288 B
  const size_t NEED = 917504;

  if (ws_size >= NEED) {
    prep<<<129, 256, 0, stream>>>((const unsigned char*)mask, flag, W, Wts);
    gemm_fused<<<512, 256, 0, stream>>>(x, Wts, bias, v, s);
    pool3<<<dim3(64, Bsz), 256, 0, stream>>>(x, s, mask, flag, out);
  } else {
    detect_mask<<<1, 256, 0, stream>>>((const unsigned char*)mask, flag);
    gemm_s_f32<<<dim3(Lsz / 64, Bsz), 256, 0, stream>>>(x, W, bias, v, s);
    win_weights<<<(Bsz * LPOOL + 255) / 256, 256, 0, stream>>>(s, mask, flag, wgt);
    pool_out<<<Bsz * Csz, 256, 0, stream>>>(x, wgt, out);
  }
}